// Round 6
// baseline (103.381 us; speedup 1.0000x reference)
//
#include <hip/hip_runtime.h>

#define DIM    64      // CELL_DIM
#define NCELLS 512
#define CC     256     // cells per cell-chunk (2 chunks)
#define KC     32      // k-rows per k-chunk  (2 chunks)
#define ROWS_PER_BLOCK 8
#define NROWS  8192

// R6 DIAGNOSTIC: exact R3 kernel (best, 81.29 us), launched TWICE.
// Second launch is idempotent (same inputs -> same outputs). The marginal
// dur_us of launch #2 = true warm kernel duration, resolving whether the
// 4-round 81-86 us plateau is kernel time, harness floor, or clock ramp.
__global__ __launch_bounds__(256, 4)
void placecells_kernel(const float* __restrict__ x,
                       const float* __restrict__ pc,
                       float* __restrict__ out)
{
    __shared__ float pcT[KC * CC];   // 32 KB

    const int tid = (int)threadIdx.x;
    const int l   = tid & 63;
    const int w   = __builtin_amdgcn_readfirstlane(tid >> 6);
    const int rowBase = (int)blockIdx.x * ROWS_PER_BLOCK + w * 2;

    float4 a00{0,0,0,0}, a10{0,0,0,0};   // rows 0/1, cell-chunk 0
    float4 a01{0,0,0,0}, a11{0,0,0,0};   // rows 0/1, cell-chunk 1

    auto stage = [&](int cc, int kc) {
        #pragma unroll
        for (int i = 0; i < 8; ++i) {
            int idx = i * 256 + tid;
            int cl  = idx >> 3;          // cell in chunk, 0..255
            int k4  = idx & 7;           // k-quad in chunk (coalesced)
            float4 v = *(const float4*)(pc + (cc * CC + cl) * DIM + kc * KC + k4 * 4);
            int pq = (cl >> 2) ^ k4;     // bank swizzle
            float* p = &pcT[(k4 * 4) * CC + pq * 4 + (cl & 3)];
            p[0 * CC] = v.x;
            p[1 * CC] = v.y;
            p[2 * CC] = v.z;
            p[3 * CC] = v.w;
        }
    };

    auto compute = [&](int kc, float4& A0, float4& A1) {
        #pragma unroll
        for (int k4 = 0; k4 < 8; ++k4) {
            float4 xv0 = *(const float4*)(x + (rowBase + 0) * DIM + kc * KC + k4 * 4);
            float4 xv1 = *(const float4*)(x + (rowBase + 1) * DIM + kc * KC + k4 * 4);
            const int pq4 = (l ^ k4) * 4;   // undo swizzle: logical quad = l
            #pragma unroll
            for (int j = 0; j < 4; ++j) {
                float4 pv = *(const float4*)(&pcT[(k4 * 4 + j) * CC + pq4]);
                float x0 = (j == 0) ? xv0.x : (j == 1) ? xv0.y : (j == 2) ? xv0.z : xv0.w;
                float x1 = (j == 0) ? xv1.x : (j == 1) ? xv1.y : (j == 2) ? xv1.z : xv1.w;
                A0.x += fabsf(x0 - pv.x); A0.y += fabsf(x0 - pv.y);
                A0.z += fabsf(x0 - pv.z); A0.w += fabsf(x0 - pv.w);
                A1.x += fabsf(x1 - pv.x); A1.y += fabsf(x1 - pv.y);
                A1.z += fabsf(x1 - pv.z); A1.w += fabsf(x1 - pv.w);
            }
        }
    };

    stage(0, 0); __syncthreads();
    compute(0, a00, a10);
    __syncthreads(); stage(0, 1); __syncthreads();
    compute(1, a00, a10);
    __syncthreads(); stage(1, 0); __syncthreads();
    compute(0, a01, a11);
    __syncthreads(); stage(1, 1); __syncthreads();
    compute(1, a01, a11);

    // ---- softmax per row over 512 cells (one wave holds a whole row) ----
    auto finish_row = [&](float4 a, float4 b, int r) {
        // min L1 == min d^2 (d >= 0) -> exact max-subtraction, no underflow
        float mn = fminf(fminf(fminf(a.x, a.y), fminf(a.z, a.w)),
                         fminf(fminf(b.x, b.y), fminf(b.z, b.w)));
        #pragma unroll
        for (int off = 32; off > 0; off >>= 1)
            mn = fminf(mn, __shfl_xor(mn, off, 64));
        float m2 = mn * mn;

        float e0 = __expf(0.5f * (m2 - a.x * a.x));
        float e1 = __expf(0.5f * (m2 - a.y * a.y));
        float e2 = __expf(0.5f * (m2 - a.z * a.z));
        float e3 = __expf(0.5f * (m2 - a.w * a.w));
        float e4 = __expf(0.5f * (m2 - b.x * b.x));
        float e5 = __expf(0.5f * (m2 - b.y * b.y));
        float e6 = __expf(0.5f * (m2 - b.z * b.z));
        float e7 = __expf(0.5f * (m2 - b.w * b.w));
        float s = ((e0 + e1) + (e2 + e3)) + ((e4 + e5) + (e6 + e7));
        #pragma unroll
        for (int off = 32; off > 0; off >>= 1)
            s += __shfl_xor(s, off, 64);
        float inv = 1.0f / s;

        float* orow = out + (size_t)(rowBase + r) * NCELLS;
        *(float4*)(orow + 4 * l)      = make_float4(e0 * inv, e1 * inv, e2 * inv, e3 * inv);
        *(float4*)(orow + CC + 4 * l) = make_float4(e4 * inv, e5 * inv, e6 * inv, e7 * inv);
    };
    finish_row(a00, a01, 0);
    finish_row(a10, a11, 1);
}

extern "C" void kernel_launch(void* const* d_in, const int* in_sizes, int n_in,
                              void* d_out, int out_size, void* d_ws, size_t ws_size,
                              hipStream_t stream)
{
    const float* x  = (const float*)d_in[0];   // (8192, 64) fp32
    const float* pc = (const float*)d_in[1];   // (512, 64) fp32
    float* out = (float*)d_out;                // (8192, 512) fp32
    // DIAGNOSTIC double-launch: marginal cost of #2 = warm kernel duration.
    placecells_kernel<<<dim3(NROWS / ROWS_PER_BLOCK), dim3(256), 0, stream>>>(x, pc, out);
    placecells_kernel<<<dim3(NROWS / ROWS_PER_BLOCK), dim3(256), 0, stream>>>(x, pc, out);
}

// Round 7
// 86.544 us; speedup vs baseline: 1.1945x; 1.1945x over previous
//
#include <hip/hip_runtime.h>

#define DIM    64
#define NCELLS 512
#define ROWS_PER_BLOCK 16
#define NROWS  8192

// R7: register-resident pc. R6 counters showed latency-bound (all pipes <35%:
// VALUBusy ~15% true, LDS ~30%, HBM 5%, conflicts 0) — the ds_read->VALU
// dependency chain was the stall, not any throughput ceiling. So: NO LDS in
// the hot loop. Block=512: thread tid holds cell tid's full k-vector as 16
// NAMED float4s (64 VGPR; named, not arrays — R1: indexed arrays spill to
// scratch). x rows are wave-uniform -> compiler scalarizes to s_load (R3
// evidence: SGPR_Count=112), so inner loop is pure VALU:
//   v_sub_f32 (1 SGPR + 1 VGPR) + v_add_f32 acc,acc,|t|
// 4 independent chains/lane -> issue-saturated. 16 rows/block in 4 groups of
// 4; per-group batched wave-shuffle + tiny-LDS cross-wave softmax reduction.
// Grid=512 -> 2 blocks/CU; LDS = 512 B.
#define CSTEP(pv, kk) \
    a0 += fabsf(xr0[kk] - (pv)); \
    a1 += fabsf(xr1[kk] - (pv)); \
    a2 += fabsf(xr2[kk] - (pv)); \
    a3 += fabsf(xr3[kk] - (pv));

#define QSTEP(Pq, q) \
    CSTEP((Pq).x, 4*(q)+0) \
    CSTEP((Pq).y, 4*(q)+1) \
    CSTEP((Pq).z, 4*(q)+2) \
    CSTEP((Pq).w, 4*(q)+3)

__global__ __launch_bounds__(512, 4)
void placecells_kernel(const float* __restrict__ x,
                       const float* __restrict__ pc,
                       float* __restrict__ out)
{
    __shared__ float redMin[2][8][4];   // [parity][wave][rowInGroup]
    __shared__ float redSum[2][8][4];

    const int tid = (int)threadIdx.x;
    const int l   = tid & 63;
    const int w   = tid >> 6;                    // wave 0..7
    const int rowBase = (int)blockIdx.x * ROWS_PER_BLOCK;

    // ---- this thread's cell (cell == tid) -> 16 float4 registers ----
    const float* pcl = pc + tid * DIM;
    float4 P0  = *(const float4*)(pcl +  0);
    float4 P1  = *(const float4*)(pcl +  4);
    float4 P2  = *(const float4*)(pcl +  8);
    float4 P3  = *(const float4*)(pcl + 12);
    float4 P4  = *(const float4*)(pcl + 16);
    float4 P5  = *(const float4*)(pcl + 20);
    float4 P6  = *(const float4*)(pcl + 24);
    float4 P7  = *(const float4*)(pcl + 28);
    float4 P8  = *(const float4*)(pcl + 32);
    float4 P9  = *(const float4*)(pcl + 36);
    float4 P10 = *(const float4*)(pcl + 40);
    float4 P11 = *(const float4*)(pcl + 44);
    float4 P12 = *(const float4*)(pcl + 48);
    float4 P13 = *(const float4*)(pcl + 52);
    float4 P14 = *(const float4*)(pcl + 56);
    float4 P15 = *(const float4*)(pcl + 60);

    auto wred_min = [&](float v) {
        #pragma unroll
        for (int off = 32; off > 0; off >>= 1) v = fminf(v, __shfl_xor(v, off, 64));
        return v;
    };
    auto wred_sum = [&](float v) {
        #pragma unroll
        for (int off = 32; off > 0; off >>= 1) v += __shfl_xor(v, off, 64);
        return v;
    };

    auto do_group = [&](int g, int par) {
        const float* xr0 = x + (size_t)(rowBase + 4 * g) * DIM;  // wave-uniform -> s_load
        const float* xr1 = xr0 + DIM;
        const float* xr2 = xr1 + DIM;
        const float* xr3 = xr2 + DIM;
        float a0 = 0.f, a1 = 0.f, a2 = 0.f, a3 = 0.f;

        QSTEP(P0,  0)  QSTEP(P1,  1)  QSTEP(P2,  2)  QSTEP(P3,  3)
        QSTEP(P4,  4)  QSTEP(P5,  5)  QSTEP(P6,  6)  QSTEP(P7,  7)
        QSTEP(P8,  8)  QSTEP(P9,  9)  QSTEP(P10, 10) QSTEP(P11, 11)
        QSTEP(P12, 12) QSTEP(P13, 13) QSTEP(P14, 14) QSTEP(P15, 15)

        // ---- softmax over the row's 512 cells (spread across 8 waves) ----
        float m0 = wred_min(a0), m1 = wred_min(a1);
        float m2 = wred_min(a2), m3 = wred_min(a3);
        if (l == 0) {
            redMin[par][w][0] = m0; redMin[par][w][1] = m1;
            redMin[par][w][2] = m2; redMin[par][w][3] = m3;
        }
        __syncthreads();
        float M0 = redMin[par][0][0], M1 = redMin[par][0][1];
        float M2 = redMin[par][0][2], M3 = redMin[par][0][3];
        #pragma unroll
        for (int ww = 1; ww < 8; ++ww) {
            M0 = fminf(M0, redMin[par][ww][0]);
            M1 = fminf(M1, redMin[par][ww][1]);
            M2 = fminf(M2, redMin[par][ww][2]);
            M3 = fminf(M3, redMin[par][ww][3]);
        }
        // min L1 == min d^2 (d >= 0) -> exact max-subtraction, args <= 0
        float e0 = __expf(0.5f * (M0 * M0 - a0 * a0));
        float e1 = __expf(0.5f * (M1 * M1 - a1 * a1));
        float e2 = __expf(0.5f * (M2 * M2 - a2 * a2));
        float e3 = __expf(0.5f * (M3 * M3 - a3 * a3));
        float s0 = wred_sum(e0), s1 = wred_sum(e1);
        float s2 = wred_sum(e2), s3 = wred_sum(e3);
        if (l == 0) {
            redSum[par][w][0] = s0; redSum[par][w][1] = s1;
            redSum[par][w][2] = s2; redSum[par][w][3] = s3;
        }
        __syncthreads();
        float S0 = redSum[par][0][0], S1 = redSum[par][0][1];
        float S2 = redSum[par][0][2], S3 = redSum[par][0][3];
        #pragma unroll
        for (int ww = 1; ww < 8; ++ww) {
            S0 += redSum[par][ww][0];
            S1 += redSum[par][ww][1];
            S2 += redSum[par][ww][2];
            S3 += redSum[par][ww][3];
        }
        float i0 = 1.0f / S0, i1 = 1.0f / S1, i2 = 1.0f / S2, i3 = 1.0f / S3;

        // cell == tid -> stores fully coalesced across the block
        out[(size_t)(rowBase + 4 * g + 0) * NCELLS + tid] = e0 * i0;
        out[(size_t)(rowBase + 4 * g + 1) * NCELLS + tid] = e1 * i1;
        out[(size_t)(rowBase + 4 * g + 2) * NCELLS + tid] = e2 * i2;
        out[(size_t)(rowBase + 4 * g + 3) * NCELLS + tid] = e3 * i3;
    };

    // parity ping-pong on the reduction scratch: >=2 barriers between reuse
    do_group(0, 0);
    do_group(1, 1);
    do_group(2, 0);
    do_group(3, 1);
}

extern "C" void kernel_launch(void* const* d_in, const int* in_sizes, int n_in,
                              void* d_out, int out_size, void* d_ws, size_t ws_size,
                              hipStream_t stream)
{
    const float* x  = (const float*)d_in[0];   // (8192, 64) fp32
    const float* pc = (const float*)d_in[1];   // (512, 64) fp32
    float* out = (float*)d_out;                // (8192, 512) fp32
    placecells_kernel<<<dim3(NROWS / ROWS_PER_BLOCK), dim3(512), 0, stream>>>(x, pc, out);
}